// Round 7
// baseline (86.732 us; speedup 1.0000x reference)
//
#include <hip/hip_runtime.h>
#include <math.h>

// Problem constants (fixed by reference)
#define BB 4
#define T 64
#define F 64
#define U 64
#define S 64
#define M 64
#define UP 65   // padded row stride (bank-conflict break for column gathers)
#define FP 65

// ws layout (floats)
#define WS_H    0        // [B, T, U]   = 16384
#define WS_SC   16384    // [B, T, F]   = 16384  (score)
#define WS_LOG  32768    // [B, M]      = 256
#define WS_CNT  33024    // [B] uint32 arrival counters

// fast tanh: tanh(x) = sign(x) * (1 - 2/(1+e^{2|x|}))
__device__ __forceinline__ float fast_tanh(float x) {
    float a = fabsf(x);
    float e = __builtin_amdgcn_exp2f(a * 2.88539008177792681f); // e^{2a}
    float r = 1.0f - 2.0f * __builtin_amdgcn_rcpf(e + 1.0f);
    return copysignf(r, x);
}

// ---------------- Kernel A: per-(b,t) row: h, output, score ----------------
// grid: B*T blocks, 256 threads (4 waves). tid = (j<<6)|l
// Also zeroes the per-batch arrival counter for k2 (poison is 0xAA).
__global__ __launch_bounds__(256) void kA_rows(
    const float* __restrict__ inputs, const float* __restrict__ Wk,
    const float* __restrict__ bk, const float* __restrict__ Wv,
    const float* __restrict__ bv, const float* __restrict__ w_s,
    float* __restrict__ ws, float* __restrict__ d_out)
{
    __shared__ float inp_s[F];
    __shared__ float part[4][64];
    __shared__ float h_s[U];
    __shared__ float out_s[F];

    const int blk = blockIdx.x;
    const int b = blk >> 6, t = blk & 63;
    const int tid = threadIdx.x;
    const int j = tid >> 6, l = tid & 63;
    const float w_last = w_s[S - 1];
    const float* inp = inputs + (b * T + t) * F;

    if (t == 0 && tid == 0)
        ((unsigned*)ws)[WS_CNT + b] = 0u;   // init arrival counter (pre-k2)

    if (tid < F) inp_s[tid] = inp[tid];
    __syncthreads();

    // h[u] = tanh(sum_f inp[f]*Wk[f,u] + bk[u]); u = l, partial over 16 f's
    {
        float acc = 0.0f;
        #pragma unroll
        for (int k = 0; k < 16; ++k) {
            int f = j * 16 + k;
            acc += inp_s[f] * Wk[f * U + l];
        }
        part[j][l] = acc;
    }
    __syncthreads();
    if (tid < U) {
        float v = part[0][tid] + part[1][tid] + part[2][tid] + part[3][tid] + bk[tid];
        float h = tanhf(v);
        h_s[tid] = h;
        ws[WS_H + (b * T + t) * U + tid] = h;
    }
    __syncthreads();

    // out[f] = sum_u h[u]*Wv[u,f] + bv[f]; f = l
    {
        float acc = 0.0f;
        #pragma unroll
        for (int k = 0; k < 16; ++k) {
            int u = j * 16 + k;
            acc += h_s[u] * Wv[u * F + l];
        }
        part[j][l] = acc;
    }
    __syncthreads();
    if (tid < F) {
        float v = part[0][tid] + part[1][tid] + part[2][tid] + part[3][tid] + bv[tid];
        out_s[tid] = v;
        d_out[2 * BB * T + (b * T + t) * F + tid] = v;  // output region
    }
    __syncthreads();

    // score[f] = sum_u fast_tanh(h[u]*out[f]*w_last); f = l
    {
        float c = out_s[l] * w_last;
        float acc = 0.0f;
        #pragma unroll
        for (int k = 0; k < 16; ++k) {
            int u = j * 16 + k;
            acc += fast_tanh(h_s[u] * c);
        }
        part[j][l] = acc;
    }
    __syncthreads();
    if (tid < F) {
        ws[WS_SC + (b * T + t) * F + tid] =
            part[0][tid] + part[1][tid] + part[2][tid] + part[3][tid];
    }
}

// ---- Kernel K2: per-(b,m): argmax/extremes/flat + logit dot.
// ---- LAST-arriving block per batch (atomic counter) runs the head inline. --
// grid: B*M blocks (256), 256 threads (4 waves).
__global__ __launch_bounds__(256) void k2_flat_logits_head(
    const float* __restrict__ inputs, const float* __restrict__ w_s,
    const float* __restrict__ mem_keys, const float* __restrict__ mem_vals,
    const float* __restrict__ d_out_const, const float* __restrict__ ws_in,
    float* __restrict__ ws, float* __restrict__ d_out)
{
    __shared__ float h_lds[T * UP];
    __shared__ float sc_lds[T * FP];
    __shared__ float out_lds[T * F];   // overwritten in-place by flat
    __shared__ int   idx_f[F];
    __shared__ int   idx_t[T];
    __shared__ float hmin_l[T], hmax_l[T];
    __shared__ float wext[2];
    __shared__ float wsum[4];
    __shared__ int   is_last;
    __shared__ float attn[M];
    __shared__ float targets[F];
    __shared__ float imp_sh;

    const int blk = blockIdx.x;
    const int b = blk >> 6, m = blk & 63;
    const int tid = threadIdx.x;
    unsigned* cnt = (unsigned*)ws + WS_CNT;

    // mem_keys row into registers (coalesced)
    float mkr[16];
    {
        const float* mk = mem_keys + m * (T * F);
        #pragma unroll
        for (int i = 0; i < 16; ++i)
            mkr[i] = mk[i * 256 + tid];
    }

    // load score, h, out for batch b
    #pragma unroll
    for (int i = 0; i < 16; ++i) {
        int id = i * 256 + tid;
        int t = id >> 6, x = id & 63;
        sc_lds[t * FP + x] = ws_in[WS_SC + b * T * F + id];
        h_lds[t * UP + x]  = ws_in[WS_H + b * T * U + id];
        out_lds[id] = d_out_const[2 * BB * T + b * T * F + id];
    }
    __syncthreads();

    // argmaxes (first occurrence -> strict >)
    if (tid < F) {
        int f = tid;
        float best = sc_lds[f];
        int bi = 0;
        for (int t = 1; t < T; ++t) {
            float v = sc_lds[t * FP + f];
            if (v > best) { best = v; bi = t; }
        }
        idx_f[f] = bi;
    } else if (tid < 128) {
        int t = tid - 64;
        float best = sc_lds[t * FP];
        int bi = 0;
        for (int f = 1; f < F; ++f) {
            float v = sc_lds[t * FP + f];
            if (v > best) { best = v; bi = f; }
        }
        idx_t[t] = bi;
    }
    __syncthreads();

    // per-t h-extremes over selected u-set; w-extremes over selected s-set
    if (tid < T) {
        int t = tid;
        float mn = 1e30f, mx = -1e30f;
        for (int i = 0; i < T; ++i) {
            float v = h_lds[t * UP + idx_t[i]];
            mn = fminf(mn, v);
            mx = fmaxf(mx, v);
        }
        hmin_l[t] = mn;
        hmax_l[t] = mx;
    } else if (tid == 64) {
        float mn = 1e30f, mx = -1e30f;
        for (int jj = 0; jj < F; ++jj) {
            float v = w_s[idx_f[jj]];
            mn = fminf(mn, v);
            mx = fmaxf(mx, v);
        }
        wext[0] = mn;
        wext[1] = mx;
    }
    __syncthreads();

    // flat in-place, then dot with mem_keys row
    float acc = 0.0f;
    {
        float wmn = wext[0], wmx = wext[1];
        #pragma unroll
        for (int i = 0; i < 16; ++i) {
            int id = i * 256 + tid;
            int t = id >> 6;
            float q = out_lds[id];
            float hmn = hmin_l[t], hmx = hmax_l[t];
            float p1 = hmn * wmn, p2 = hmn * wmx, p3 = hmx * wmn, p4 = hmx * wmx;
            float pwmax = fmaxf(fmaxf(p1, p2), fmaxf(p3, p4));
            float pwmin = fminf(fminf(p1, p2), fminf(p3, p4));
            float mval = (q >= 0.0f) ? q * pwmax : q * pwmin;
            acc += tanhf(mval) * mkr[i];
        }
    }
    #pragma unroll
    for (int off = 32; off; off >>= 1)
        acc += __shfl_down(acc, off, 64);
    if ((tid & 63) == 0) wsum[tid >> 6] = acc;
    __syncthreads();

    // publish logit, then arrive; last block (old == M-1) runs the head
    if (tid == 0) {
        ws[WS_LOG + b * M + m] = wsum[0] + wsum[1] + wsum[2] + wsum[3];
        unsigned old = __hip_atomic_fetch_add(&cnt[b], 1u,
                           __ATOMIC_ACQ_REL, __HIP_MEMORY_SCOPE_AGENT);
        is_last = (old == M - 1);
    }
    __syncthreads();
    if (!is_last) return;

    const float* inp = inputs + b * T * F;

    // softmax over 64 logits (one wave); agent-scope loads (cross-XCD safe)
    if (tid < M) {
        float lg = __hip_atomic_load((const float*)ws + WS_LOG + b * M + tid,
                                     __ATOMIC_ACQUIRE, __HIP_MEMORY_SCOPE_AGENT);
        float mx = lg;
        #pragma unroll
        for (int off = 32; off; off >>= 1)
            mx = fmaxf(mx, __shfl_xor(mx, off, 64));
        float e = __builtin_amdgcn_exp2f((lg - mx) * 1.442695040888963f);
        float s = e;
        #pragma unroll
        for (int off = 32; off; off >>= 1)
            s += __shfl_xor(s, off, 64);
        attn[tid] = e / s;
        if (tid == 0) imp_sh = 1.0f / s;  // max(attn) = exp(0)/s
    }
    __syncthreads();

    // targets[f] = sum_m attn[m] * mem_vals[m,f]
    if (tid < F) {
        float a2 = 0.0f;
        #pragma unroll 8
        for (int mm = 0; mm < M; ++mm)
            a2 += attn[mm] * mem_vals[mm * F + tid];
        targets[tid] = a2;
    }
    __syncthreads();

    // dist + importances: 4 lanes per t-row
    {
        float imp = imp_sh;
        int t = tid >> 2;
        int j = tid & 3;
        float ss = 0.0f;
        #pragma unroll
        for (int k = 0; k < 16; ++k) {
            int f = j + 4 * k;
            float d = inp[t * F + f] - targets[f];
            ss += d * d;
        }
        ss += __shfl_down(ss, 2, 4);
        ss += __shfl_down(ss, 1, 4);
        if (j == 0) {
            float nrm = sqrtf(ss);
            float hs = fminf(0.2f * nrm + 0.5f, 1.0f);  // hard_sigmoid, x>=0
            d_out[b * T + t] = 0.5f - hs;               // dist region
            d_out[BB * T + b * T + t] = imp;            // importances region
        }
    }
}

extern "C" void kernel_launch(void* const* d_in, const int* in_sizes, int n_in,
                              void* d_out, int out_size, void* d_ws, size_t ws_size,
                              hipStream_t stream) {
    const float* inputs   = (const float*)d_in[0];
    const float* Wk       = (const float*)d_in[1];
    const float* bk       = (const float*)d_in[2];
    const float* Wv       = (const float*)d_in[3];
    const float* bv       = (const float*)d_in[4];
    const float* w_s      = (const float*)d_in[5];
    const float* mem_keys = (const float*)d_in[6];
    const float* mem_vals = (const float*)d_in[7];
    float* out = (float*)d_out;
    float* ws  = (float*)d_ws;

    kA_rows<<<dim3(BB * T), dim3(256), 0, stream>>>(inputs, Wk, bk, Wv, bv, w_s, ws, out);
    k2_flat_logits_head<<<dim3(BB * M), dim3(256), 0, stream>>>(
        inputs, w_s, mem_keys, mem_vals, out, ws, ws, out);
}

// Round 8
// 82.123 us; speedup vs baseline: 1.0561x; 1.0561x over previous
//
#include <hip/hip_runtime.h>
#include <math.h>

// Problem constants (fixed by reference)
#define BB 4
#define T 64
#define F 64
#define U 64
#define S 64
#define M 64
#define UP 65   // padded row stride (bank-conflict break for column gathers)
#define FP 65

// ws layout (floats)
#define WS_H    0        // [B, T, U]   = 16384
#define WS_SC   16384    // [B, T, F]   = 16384  (score)
#define WS_LOG  32768    // [B, M]      = 256

// fast tanh: tanh(x) = sign(x) * (1 - 2/(1+e^{2|x|}))
__device__ __forceinline__ float fast_tanh(float x) {
    float a = fabsf(x);
    float e = __builtin_amdgcn_exp2f(a * 2.88539008177792681f); // e^{2a}
    float r = 1.0f - 2.0f * __builtin_amdgcn_rcpf(e + 1.0f);
    return copysignf(r, x);
}

// ---------------- Kernel A: per-(b,t) row: h, output, score ----------------
// grid: B*T blocks, 256 threads (4 waves). tid = (j<<6)|l
__global__ __launch_bounds__(256) void kA_rows(
    const float* __restrict__ inputs, const float* __restrict__ Wk,
    const float* __restrict__ bk, const float* __restrict__ Wv,
    const float* __restrict__ bv, const float* __restrict__ w_s,
    float* __restrict__ ws, float* __restrict__ d_out)
{
    __shared__ float inp_s[F];
    __shared__ float part[4][64];
    __shared__ float h_s[U];
    __shared__ float out_s[F];

    const int blk = blockIdx.x;
    const int b = blk >> 6, t = blk & 63;
    const int tid = threadIdx.x;
    const int j = tid >> 6, l = tid & 63;
    const float w_last = w_s[S - 1];
    const float* inp = inputs + (b * T + t) * F;

    if (tid < F) inp_s[tid] = inp[tid];
    __syncthreads();

    // h[u] = tanh(sum_f inp[f]*Wk[f,u] + bk[u]); u = l, partial over 16 f's
    {
        float acc = 0.0f;
        #pragma unroll
        for (int k = 0; k < 16; ++k) {
            int f = j * 16 + k;
            acc += inp_s[f] * Wk[f * U + l];
        }
        part[j][l] = acc;
    }
    __syncthreads();
    if (tid < U) {
        float v = part[0][tid] + part[1][tid] + part[2][tid] + part[3][tid] + bk[tid];
        float h = tanhf(v);
        h_s[tid] = h;
        ws[WS_H + (b * T + t) * U + tid] = h;
    }
    __syncthreads();

    // out[f] = sum_u h[u]*Wv[u,f] + bv[f]; f = l
    {
        float acc = 0.0f;
        #pragma unroll
        for (int k = 0; k < 16; ++k) {
            int u = j * 16 + k;
            acc += h_s[u] * Wv[u * F + l];
        }
        part[j][l] = acc;
    }
    __syncthreads();
    if (tid < F) {
        float v = part[0][tid] + part[1][tid] + part[2][tid] + part[3][tid] + bv[tid];
        out_s[tid] = v;
        d_out[2 * BB * T + (b * T + t) * F + tid] = v;  // output region
    }
    __syncthreads();

    // score[f] = sum_u fast_tanh(h[u]*out[f]*w_last); f = l
    {
        float c = out_s[l] * w_last;
        float acc = 0.0f;
        #pragma unroll
        for (int k = 0; k < 16; ++k) {
            int u = j * 16 + k;
            acc += fast_tanh(h_s[u] * c);
        }
        part[j][l] = acc;
    }
    __syncthreads();
    if (tid < F) {
        ws[WS_SC + (b * T + t) * F + tid] =
            part[0][tid] + part[1][tid] + part[2][tid] + part[3][tid];
    }
}

// ---- Kernel K2: per-(b,m): redundant argmax/extremes/flat + logit dot ----
// grid: B*M blocks (256), 256 threads (4 waves).
__global__ __launch_bounds__(256) void k2_flat_logits(
    const float* __restrict__ w_s, const float* __restrict__ mem_keys,
    const float* __restrict__ d_out_const, const float* __restrict__ ws_in,
    float* __restrict__ ws)
{
    __shared__ float h_lds[T * UP];
    __shared__ float sc_lds[T * FP];
    __shared__ float out_lds[T * F];   // overwritten in-place by flat
    __shared__ int   idx_f[F];
    __shared__ int   idx_t[T];
    __shared__ float hmin_l[T], hmax_l[T];
    __shared__ float wext[2];
    __shared__ float wsum[4];

    const int blk = blockIdx.x;
    const int b = blk >> 6, m = blk & 63;
    const int tid = threadIdx.x;

    // mem_keys row into registers (coalesced)
    float mkr[16];
    {
        const float* mk = mem_keys + m * (T * F);
        #pragma unroll
        for (int i = 0; i < 16; ++i)
            mkr[i] = mk[i * 256 + tid];
    }

    // load score, h, out for batch b
    #pragma unroll
    for (int i = 0; i < 16; ++i) {
        int id = i * 256 + tid;
        int t = id >> 6, x = id & 63;
        sc_lds[t * FP + x] = ws_in[WS_SC + b * T * F + id];
        h_lds[t * UP + x]  = ws_in[WS_H + b * T * U + id];
        out_lds[id] = d_out_const[2 * BB * T + b * T * F + id];
    }
    __syncthreads();

    // argmaxes (first occurrence -> strict >)
    if (tid < F) {
        int f = tid;
        float best = sc_lds[f];
        int bi = 0;
        for (int t = 1; t < T; ++t) {
            float v = sc_lds[t * FP + f];
            if (v > best) { best = v; bi = t; }
        }
        idx_f[f] = bi;
    } else if (tid < 128) {
        int t = tid - 64;
        float best = sc_lds[t * FP];
        int bi = 0;
        for (int f = 1; f < F; ++f) {
            float v = sc_lds[t * FP + f];
            if (v > best) { best = v; bi = f; }
        }
        idx_t[t] = bi;
    }
    __syncthreads();

    // per-t h-extremes over selected u-set; w-extremes over selected s-set
    if (tid < T) {
        int t = tid;
        float mn = 1e30f, mx = -1e30f;
        for (int i = 0; i < T; ++i) {
            float v = h_lds[t * UP + idx_t[i]];
            mn = fminf(mn, v);
            mx = fmaxf(mx, v);
        }
        hmin_l[t] = mn;
        hmax_l[t] = mx;
    } else if (tid == 64) {
        float mn = 1e30f, mx = -1e30f;
        for (int jj = 0; jj < F; ++jj) {
            float v = w_s[idx_f[jj]];
            mn = fminf(mn, v);
            mx = fmaxf(mx, v);
        }
        wext[0] = mn;
        wext[1] = mx;
    }
    __syncthreads();

    // flat in-place, then dot with mem_keys row
    float acc = 0.0f;
    {
        float wmn = wext[0], wmx = wext[1];
        #pragma unroll
        for (int i = 0; i < 16; ++i) {
            int id = i * 256 + tid;
            int t = id >> 6;
            float q = out_lds[id];
            float hmn = hmin_l[t], hmx = hmax_l[t];
            float p1 = hmn * wmn, p2 = hmn * wmx, p3 = hmx * wmn, p4 = hmx * wmx;
            float pwmax = fmaxf(fmaxf(p1, p2), fmaxf(p3, p4));
            float pwmin = fminf(fminf(p1, p2), fminf(p3, p4));
            float mval = (q >= 0.0f) ? q * pwmax : q * pwmin;
            acc += tanhf(mval) * mkr[i];
        }
    }
    #pragma unroll
    for (int off = 32; off; off >>= 1)
        acc += __shfl_down(acc, off, 64);
    if ((tid & 63) == 0) wsum[tid >> 6] = acc;
    __syncthreads();
    if (tid == 0)
        ws[WS_LOG + b * M + m] = wsum[0] + wsum[1] + wsum[2] + wsum[3];
}

// ---------------- Kernel K3: softmax + targets + dist/importances ----------
// grid: B blocks, 256 threads
__global__ __launch_bounds__(256) void k3_head(
    const float* __restrict__ inputs, const float* __restrict__ mem_vals,
    const float* __restrict__ ws_in, float* __restrict__ d_out)
{
    __shared__ float attn[M];
    __shared__ float targets[F];
    __shared__ float imp_sh;

    const int b = blockIdx.x;
    const int tid = threadIdx.x;
    const float* inp = inputs + b * T * F;

    if (tid < M) {
        float l = ws_in[WS_LOG + b * M + tid];
        float mx = l;
        #pragma unroll
        for (int off = 32; off; off >>= 1)
            mx = fmaxf(mx, __shfl_xor(mx, off, 64));
        float e = __builtin_amdgcn_exp2f((l - mx) * 1.442695040888963f);
        float s = e;
        #pragma unroll
        for (int off = 32; off; off >>= 1)
            s += __shfl_xor(s, off, 64);
        attn[tid] = e / s;
        if (tid == 0) imp_sh = 1.0f / s;  // max(attn) = exp(0)/s
    }
    __syncthreads();

    if (tid < F) {
        float acc = 0.0f;
        #pragma unroll 8
        for (int m = 0; m < M; ++m)
            acc += attn[m] * mem_vals[m * F + tid];
        targets[tid] = acc;
    }
    __syncthreads();

    // dist: 4 lanes per t-row
    {
        float imp = imp_sh;
        int t = tid >> 2;
        int j = tid & 3;
        float ss = 0.0f;
        #pragma unroll
        for (int k = 0; k < 16; ++k) {
            int f = j + 4 * k;
            float d = inp[t * F + f] - targets[f];
            ss += d * d;
        }
        ss += __shfl_down(ss, 2, 4);
        ss += __shfl_down(ss, 1, 4);
        if (j == 0) {
            float nrm = sqrtf(ss);
            float hs = fminf(0.2f * nrm + 0.5f, 1.0f);  // hard_sigmoid, x>=0
            d_out[b * T + t] = 0.5f - hs;               // dist region
            d_out[BB * T + b * T + t] = imp;            // importances region
        }
    }
}

extern "C" void kernel_launch(void* const* d_in, const int* in_sizes, int n_in,
                              void* d_out, int out_size, void* d_ws, size_t ws_size,
                              hipStream_t stream) {
    const float* inputs   = (const float*)d_in[0];
    const float* Wk       = (const float*)d_in[1];
    const float* bk       = (const float*)d_in[2];
    const float* Wv       = (const float*)d_in[3];
    const float* bv       = (const float*)d_in[4];
    const float* w_s      = (const float*)d_in[5];
    const float* mem_keys = (const float*)d_in[6];
    const float* mem_vals = (const float*)d_in[7];
    float* out = (float*)d_out;
    float* ws  = (float*)d_ws;

    kA_rows<<<dim3(BB * T), dim3(256), 0, stream>>>(inputs, Wk, bk, Wv, bv, w_s, ws, out);
    k2_flat_logits<<<dim3(BB * M), dim3(256), 0, stream>>>(w_s, mem_keys, out, ws, ws);
    k3_head<<<dim3(BB), dim3(256), 0, stream>>>(inputs, mem_vals, ws, out);
}